// Round 1
// baseline (359.070 us; speedup 1.0000x reference)
//
#include <hip/hip_runtime.h>

// ChemResBlock: S=16, A=512, F=64, L=12, 3 layers x 2 convs (shared weights per layer).
// Main path: bf16 MFMA (16x16x32) GEMMs with f32 accumulate.
//   GEMM1 per s: connT (6144x512) x xT^T (stored [f][k]) -> ncv (6144x64) bf16
//   GEMM2:       ncv (8192x768) x wT2^T (stored [o][l*64+f]) -> out (8192x64)
//   epilogue: + bondW (precomputed bond*w tail), + node (even convs), ReLU,
//             write xT_next bf16 (or f32 d_out on conv 5).

typedef __attribute__((ext_vector_type(8))) short bf16x8;   // 8 bf16 in 4 VGPRs
typedef __attribute__((ext_vector_type(4))) float f32x4;
typedef unsigned short u16;
typedef unsigned int u32;

__device__ __forceinline__ u16 f2bf(float f) {
  union { float f; u32 u; } x; x.f = f;
  u32 r = x.u + 0x7fffu + ((x.u >> 16) & 1u);   // round-to-nearest-even
  return (u16)(r >> 16);
}

__device__ __forceinline__ void gload16(const void* g, void* l) {
  __builtin_amdgcn_global_load_lds((const __attribute__((address_space(1))) u32*)g,
                                   (__attribute__((address_space(3))) u32*)l, 16, 0, 0);
}

// ---------- prep kernels ----------

// conn (S,A,A,L) f32 -> connT [s][(a*12+l)][k=512] bf16   (per-(s,a) 512x12 -> 12x512 transpose)
__global__ __launch_bounds__(256) void k_conn_bf16(const float* __restrict__ conn,
                                                   u16* __restrict__ connT) {
  __shared__ float lds[512 * 13];            // [k][13] pad to break bank stride
  const int blk = blockIdx.x;                // s*512 + a
  const int tid = threadIdx.x;
  const float4* src = (const float4*)(conn + (size_t)blk * 6144);
  for (int j = tid; j < 1536; j += 256) {
    float4 v = src[j];
    int e = j * 4;
    lds[((e + 0) / 12) * 13 + ((e + 0) % 12)] = v.x;
    lds[((e + 1) / 12) * 13 + ((e + 1) % 12)] = v.y;
    lds[((e + 2) / 12) * 13 + ((e + 2) % 12)] = v.z;
    lds[((e + 3) / 12) * 13 + ((e + 3) % 12)] = v.w;
  }
  __syncthreads();
  ushort4* dst = (ushort4*)(connT + (size_t)blk * 6144);
  for (int j = tid; j < 1536; j += 256) {
    int o = j * 4;
    int l = o >> 9, k0 = o & 511;            // 512 % 4 == 0: no l-crossing
    ushort4 w;
    w.x = f2bf(lds[(k0 + 0) * 13 + l]);
    w.y = f2bf(lds[(k0 + 1) * 13 + l]);
    w.z = f2bf(lds[(k0 + 2) * 13 + l]);
    w.w = f2bf(lds[(k0 + 3) * 13 + l]);
    dst[j] = w;
  }
}

// filters (3,64,12,66) f32 -> wT2 [i][o][l*64+f] bf16 (drop bond cols 64,65)
__global__ __launch_bounds__(256) void k_w_bf16(const float* __restrict__ filters,
                                                u16* __restrict__ wT2) {
  int tid = blockIdx.x * 256 + threadIdx.x;  // < 3*64*768 = 147456
  int i = tid / 49152;
  int rem = tid - i * 49152;
  int o = rem / 768;
  int lf = rem - o * 768;
  int l = lf >> 6, f = lf & 63;
  wT2[tid] = f2bf(filters[((size_t)((i * 64 + o) * 12 + l)) * 66 + f]);
}

// bondW[i][s*512+a][o] = sum_{l,j} bond[s,a,l,j] * filters[i,o,l,64+j]   (f32)
__global__ __launch_bounds__(192) void k_bondw(const float* __restrict__ bond,
                                               const float* __restrict__ filters,
                                               float* __restrict__ bondW) {
  int blk = blockIdx.x;                      // s*512 + a
  int t = threadIdx.x;                       // 192 = 3 filters x 64 o
  __shared__ float lb[24];
  if (t < 24) lb[t] = bond[(size_t)blk * 24 + t];
  __syncthreads();
  int i = t >> 6, o = t & 63;
  float acc = 0.f;
#pragma unroll
  for (int l = 0; l < 12; ++l) {
    const float* wr = filters + ((size_t)((i * 64 + o) * 12 + l)) * 66 + 64;
    acc += lb[l * 2 + 0] * wr[0] + lb[l * 2 + 1] * wr[1];
  }
  bondW[(size_t)i * 524288 + (size_t)blk * 64 + o] = acc;
}

// node (S,A,F) f32 -> xT [s][f][a] bf16
__global__ __launch_bounds__(256) void k_xt0(const float* __restrict__ node,
                                             u16* __restrict__ xT) {
  int tid = blockIdx.x * 256 + threadIdx.x;  // < 524288; layout linear in (s,f,a)
  int s = tid >> 15, rem = tid & 32767;
  int f = rem >> 9, a = rem & 511;
  xT[tid] = f2bf(node[((size_t)(s * 512 + a)) * 64 + f]);
}

// ---------- GEMM staging helper ----------
// LDS tile layout: [row][32 k] bf16 (64 B rows), 16B-slot XOR swizzle:
// LDS[row][slot] holds global slot (slot ^ ((row>>1)&3)) -> conflict-free b128 frag reads.
__device__ __forceinline__ void stage_ab(const u16* __restrict__ Ab, const u16* __restrict__ Bb,
                                         int kstep, int K, int nA,
                                         u16* lA, u16* lB, int wid, int rsub, int slot) {
  for (int i = wid; i < nA + 4; i += 4) {
    const int isA = (i < nA);
    const int r0i = (isA ? i : i - nA) << 4;
    const int row = r0i + rsub;
    const int ss = slot ^ ((row >> 1) & 3);
    const u16* src = (isA ? Ab : Bb) + (size_t)row * K + kstep * 32 + ss * 8;
    u16* dst = (isA ? lA : lB) + r0i * 32;   // wave-uniform; HW adds lane*16
    gload16(src, dst);
  }
}

// ---------- GEMM1: ncv = connT x x  (per s: 6144x512 * 512x64) ----------
__global__ __launch_bounds__(256) void k_gemm1(const u16* __restrict__ connT,
                                               const u16* __restrict__ xT,
                                               u16* __restrict__ ncv) {
  const int s = blockIdx.y;
  const int row0 = blockIdx.x * 128;
  const u16* Ab = connT + (size_t)s * 3145728 + (size_t)row0 * 512;
  const u16* Bb = xT + (size_t)s * 32768;
  __shared__ __align__(16) u16 lA[2][128 * 32];
  __shared__ __align__(16) u16 lB[2][64 * 32];
  const int tid = threadIdx.x, lane = tid & 63, wid = tid >> 6;
  const int rsub = lane >> 2, slot = lane & 3;
  const int r = lane & 15, g = lane >> 4;

  f32x4 acc[2][4] = {};

  stage_ab(Ab, Bb, 0, 512, 8, lA[0], lB[0], wid, rsub, slot);
  __syncthreads();
  for (int st = 0; st < 16; ++st) {
    const int cur = st & 1;
    if (st < 15) stage_ab(Ab, Bb, st + 1, 512, 8, lA[cur ^ 1], lB[cur ^ 1], wid, rsub, slot);
    bf16x8 av[2], bv[4];
#pragma unroll
    for (int t = 0; t < 2; ++t) {
      int row = wid * 32 + t * 16 + r;
      av[t] = *(const bf16x8*)&lA[cur][row * 32 + ((g ^ ((row >> 1) & 3)) << 3)];
    }
#pragma unroll
    for (int c = 0; c < 4; ++c) {
      int col = c * 16 + r;
      bv[c] = *(const bf16x8*)&lB[cur][col * 32 + ((g ^ ((col >> 1) & 3)) << 3)];
    }
#pragma unroll
    for (int t = 0; t < 2; ++t)
#pragma unroll
      for (int c = 0; c < 4; ++c)
        acc[t][c] = __builtin_amdgcn_mfma_f32_16x16x32_bf16(av[t], bv[c], acc[t][c], 0, 0, 0);
    __syncthreads();
  }
  // epilogue: D layout col=lane&15, row=(lane>>4)*4+r2  -> ncv bf16
  u16* out = ncv + (size_t)s * 393216 + (size_t)row0 * 64;
#pragma unroll
  for (int t = 0; t < 2; ++t)
#pragma unroll
    for (int c = 0; c < 4; ++c)
#pragma unroll
      for (int r2 = 0; r2 < 4; ++r2) {
        int row = wid * 32 + t * 16 + g * 4 + r2;
        int col = c * 16 + r;
        out[row * 64 + col] = f2bf(acc[t][c][r2]);
      }
}

// ---------- GEMM2: out = ncv x w^T + bondW (+node) , ReLU ----------
__global__ __launch_bounds__(256) void k_gemm2(const u16* __restrict__ ncv,
                                               const u16* __restrict__ wT2i,
                                               const float* __restrict__ bW,
                                               const float* __restrict__ node,
                                               float* __restrict__ outF,
                                               u16* __restrict__ xTn,
                                               int addNode, int writeF32) {
  const int row0 = blockIdx.x * 64;
  const u16* Ab = ncv + (size_t)row0 * 768;
  const u16* Bb = wT2i;
  __shared__ __align__(16) u16 lA[2][64 * 32];
  __shared__ __align__(16) u16 lB[2][64 * 32];
  const int tid = threadIdx.x, lane = tid & 63, wid = tid >> 6;
  const int rsub = lane >> 2, slot = lane & 3;
  const int r = lane & 15, g = lane >> 4;

  f32x4 acc[4] = {};

  stage_ab(Ab, Bb, 0, 768, 4, lA[0], lB[0], wid, rsub, slot);
  __syncthreads();
  for (int st = 0; st < 24; ++st) {
    const int cur = st & 1;
    if (st < 23) stage_ab(Ab, Bb, st + 1, 768, 4, lA[cur ^ 1], lB[cur ^ 1], wid, rsub, slot);
    bf16x8 av, bv[4];
    {
      int row = wid * 16 + r;
      av = *(const bf16x8*)&lA[cur][row * 32 + ((g ^ ((row >> 1) & 3)) << 3)];
    }
#pragma unroll
    for (int c = 0; c < 4; ++c) {
      int col = c * 16 + r;
      bv[c] = *(const bf16x8*)&lB[cur][col * 32 + ((g ^ ((col >> 1) & 3)) << 3)];
    }
#pragma unroll
    for (int c = 0; c < 4; ++c)
      acc[c] = __builtin_amdgcn_mfma_f32_16x16x32_bf16(av, bv[c], acc[c], 0, 0, 0);
    __syncthreads();
  }
#pragma unroll
  for (int c = 0; c < 4; ++c)
#pragma unroll
    for (int r2 = 0; r2 < 4; ++r2) {
      int m = row0 + wid * 16 + g * 4 + r2;
      int o = c * 16 + r;
      float v = acc[c][r2] + bW[(size_t)m * 64 + o];
      if (addNode) v += node[(size_t)m * 64 + o];
      v = fmaxf(v, 0.f);
      if (writeF32) {
        outF[(size_t)m * 64 + o] = v;
      } else {
        int s2 = m >> 9, a2 = m & 511;
        xTn[((size_t)(s2 * 64 + o)) * 512 + a2] = f2bf(v);
      }
    }
}

// ---------- fallback (f32, correct, slow) if ws too small ----------
__global__ __launch_bounds__(256) void k_fb_conv(const float* __restrict__ x,
                                                 const float* __restrict__ conn,
                                                 const float* __restrict__ bond,
                                                 const float* __restrict__ filt,
                                                 const float* __restrict__ node,
                                                 float* __restrict__ out, int addNode) {
  const int s = blockIdx.y, a = blockIdx.x;
  const int t = threadIdx.x;
  const int f = t & 63, lg = t >> 6;         // lg handles l = lg*3 .. lg*3+2
  __shared__ float ncv[12 * 64];
  __shared__ float red[4][64];
  const float* cb = conn + ((size_t)(s * 512 + a)) * 6144;
  const float* xb = x + (size_t)s * 32768;
  float a0 = 0.f, a1 = 0.f, a2 = 0.f;
  for (int k = 0; k < 512; ++k) {
    float xv = xb[k * 64 + f];
    const float* cr = cb + k * 12 + lg * 3;
    a0 += cr[0] * xv; a1 += cr[1] * xv; a2 += cr[2] * xv;
  }
  ncv[(lg * 3 + 0) * 64 + f] = a0;
  ncv[(lg * 3 + 1) * 64 + f] = a1;
  ncv[(lg * 3 + 2) * 64 + f] = a2;
  __syncthreads();
  float p = 0.f;
  for (int l = lg * 3; l < lg * 3 + 3; ++l) {
    const float* wr = filt + ((size_t)(f * 12 + l)) * 66;   // o = f
    float q = 0.f;
    for (int f2 = 0; f2 < 64; ++f2) q += ncv[l * 64 + f2] * wr[f2];
    q += bond[((size_t)(s * 512 + a) * 12 + l) * 2 + 0] * wr[64];
    q += bond[((size_t)(s * 512 + a) * 12 + l) * 2 + 1] * wr[65];
    p += q;
  }
  red[lg][f] = p;
  __syncthreads();
  if (t < 64) {
    float v = red[0][t] + red[1][t] + red[2][t] + red[3][t];
    if (addNode) v += node[((size_t)(s * 512 + a)) * 64 + t];
    out[((size_t)(s * 512 + a)) * 64 + t] = fmaxf(v, 0.f);
  }
}

extern "C" void kernel_launch(void* const* d_in, const int* in_sizes, int n_in,
                              void* d_out, int out_size, void* d_ws, size_t ws_size,
                              hipStream_t stream) {
  (void)in_sizes; (void)n_in; (void)out_size;
  const float* node    = (const float*)d_in[0];
  const float* conn    = (const float*)d_in[1];
  const float* bond    = (const float*)d_in[2];
  const float* filters = (const float*)d_in[3];
  float* outF = (float*)d_out;

  const size_t OFF_CONNT = 0;           // 16*6144*512*2   = 100,663,296
  const size_t OFF_NCV   = 100663296;   // 16*6144*64*2    =  12,582,912
  const size_t OFF_XTA   = 113246208;   // 16*64*512*2     =   1,048,576
  const size_t OFF_XTB   = 114294784;   //                     1,048,576
  const size_t OFF_WT2   = 115343360;   // 3*64*768*2      =     294,912
  const size_t OFF_BW    = 115638272;   // 3*16*512*64*4   =   6,291,456
  const size_t WS_NEED   = 121929728;

  if (ws_size >= WS_NEED) {
    unsigned char* ws = (unsigned char*)d_ws;
    u16* connT = (u16*)(ws + OFF_CONNT);
    u16* ncv   = (u16*)(ws + OFF_NCV);
    u16* xTa   = (u16*)(ws + OFF_XTA);
    u16* xTb   = (u16*)(ws + OFF_XTB);
    u16* wT2   = (u16*)(ws + OFF_WT2);
    float* bW  = (float*)(ws + OFF_BW);

    k_conn_bf16<<<dim3(8192), dim3(256), 0, stream>>>(conn, connT);
    k_w_bf16<<<dim3(576), dim3(256), 0, stream>>>(filters, wT2);
    k_bondw<<<dim3(8192), dim3(192), 0, stream>>>(bond, filters, bW);
    k_xt0<<<dim3(2048), dim3(256), 0, stream>>>(node, xTa);

    u16* xc = xTa; u16* xn = xTb;
    for (int j = 0; j < 6; ++j) {
      int i = j >> 1;
      k_gemm1<<<dim3(48, 16), dim3(256), 0, stream>>>(connT, xc, ncv);
      k_gemm2<<<dim3(128), dim3(256), 0, stream>>>(ncv, wT2 + (size_t)i * 49152,
                                                   bW + (size_t)i * 524288, node,
                                                   outF, xn, j & 1, j == 5);
      u16* tmp = xc; xc = xn; xn = tmp;
    }
  } else {
    // f32 fallback: ping-pong node -> ws -> d_out ... -> d_out
    float* buf = (float*)d_ws;
    const float* xc = node;
    for (int j = 0; j < 6; ++j) {
      int i = j >> 1;
      float* dst = (j & 1) ? outF : buf;
      k_fb_conv<<<dim3(512, 16), dim3(256), 0, stream>>>(xc, conn, bond,
                                                         filters + (size_t)i * 50688,
                                                         node, dst, j & 1);
      xc = dst;
    }
  }
}